// Round 1
// baseline (243.658 us; speedup 1.0000x reference)
//
#include <hip/hip_runtime.h>

typedef _Float16 half8 __attribute__((ext_vector_type(8)));
typedef _Float16 half4v __attribute__((ext_vector_type(4)));
typedef _Float16 half2v __attribute__((ext_vector_type(2)));
typedef float floatx4 __attribute__((ext_vector_type(4)));

#define AS3 __attribute__((address_space(3)))
#define AS1 __attribute__((address_space(1)))

// async global->LDS, 16B per lane, wave-uniform LDS base + lane*16
__device__ __forceinline__ void gload_lds16(const _Float16* g, _Float16* l) {
    __builtin_amdgcn_global_load_lds((AS1 void*)g, (AS3 void*)l, 16, 0, 0);
}

// ---------------- fused f32 -> f16 convert of all three inputs ----------------
__global__ __launch_bounds__(256) void cvt_all(const float* __restrict__ x,
                                               const float* __restrict__ wq,
                                               const float* __restrict__ wp,
                                               _Float16* __restrict__ xh,
                                               _Float16* __restrict__ wqh,
                                               _Float16* __restrict__ wph) {
    long i = (long)blockIdx.x * 256 + threadIdx.x;   // float4 index
    const float4* src; half4v* dst; long off;
    if (i < 2097152)      { src = (const float4*)x;  dst = (half4v*)xh;  off = i; }
    else if (i < 2883584) { src = (const float4*)wq; dst = (half4v*)wqh; off = i - 2097152; }
    else                  { src = (const float4*)wp; dst = (half4v*)wph; off = i - 2883584; }
    float4 v = src[off];
    half4v h = {(_Float16)v.x, (_Float16)v.y, (_Float16)v.z, (_Float16)v.w};
    dst[off] = h;
}

// ---------------- TN GEMM, global_load_lds pipeline, XOR-swizzled ------------
// C[M,N] = A[M,K] * B[N,K]^T. 128x128 tile, BK=32, 256 threads, dbuf LDS.
// R7: staging via __builtin_amdgcn_global_load_lds (m97/m103 structure,
// 874-912 TF at this tile). LDS dest is linear (wave base + lane*16); the
// bank-conflict XOR swizzle is folded into the per-lane GLOBAL source chunk
// (m173 pattern): lane at LDS chunk (tid&3) of row r loads global chunk
// (tid&3)^((r>>1)&3). Content at LDS slot s of row r = global chunk
// s^((r>>1)&3) — identical to the R5 reg-staged layout, so the fragment
// read path (aoff = (quad^swz)*8) is unchanged and stays conflict-free.
// One barrier per K-step; next-tile loads issued right after the barrier so
// the vmcnt drain lands at the NEXT barrier, one full compute phase later.
// Columns >= split are written TRANSPOSED into Vt[bh*64+d][n] (8B half4
// stores; m-rows are consecutive n there). Vt path assumes M,N layout of the
// QKV problem (row>>10 = b, (col-split)>>6 = h).
__global__ __launch_bounds__(256, 4) void gemm_tn(
    const _Float16* __restrict__ A, const _Float16* __restrict__ B,
    _Float16* __restrict__ Ch, int ldc, _Float16* __restrict__ Vt, int split,
    float* __restrict__ Cf, const float* __restrict__ bias,
    int M, int Nn, int K)
{
    __shared__ _Float16 sA[2][128 * 32];
    __shared__ _Float16 sB[2][128 * 32];
    const int tid  = threadIdx.x;
    const int lane = tid & 63, wave = tid >> 6;
    const int quad = lane >> 4, l16 = lane & 15;
    const int wr = wave >> 1, wc = wave & 1;
    const long m0 = (long)blockIdx.x * 128, n0 = (long)blockIdx.y * 128;

    // thread tid lands (via lane*16B) at LDS chunk (tid&3) of row srow (and
    // srow+64); it must therefore LOAD global chunk (tid&3)^((srow>>1)&3).
    const int srow = tid >> 2;
    const int csw = ((tid & 3) ^ ((srow >> 1) & 3)) * 8;   // pre-swizzled source chunk
    const _Float16* gA0 = A + (m0 + srow) * (long)K + csw;
    const _Float16* gA1 = A + (m0 + srow + 64) * (long)K + csw;
    const _Float16* gB0 = B + (n0 + srow) * (long)K + csw;
    const _Float16* gB1 = B + (n0 + srow + 64) * (long)K + csw;
    const int wbase = wave << 4;        // first row this wave stages (16 rows/wave)

#define STAGE(bf, koff)                                                  \
    do {                                                                 \
        gload_lds16(gA0 + (koff), &sA[bf][wbase * 32]);                  \
        gload_lds16(gA1 + (koff), &sA[bf][(wbase + 64) * 32]);           \
        gload_lds16(gB0 + (koff), &sB[bf][wbase * 32]);                  \
        gload_lds16(gB1 + (koff), &sB[bf][(wbase + 64) * 32]);           \
    } while (0)

    const int swz = (l16 >> 1) & 3;
    const int aoff = ((quad ^ swz) * 8);

    floatx4 acc[4][4] = {};
    const int nk = K >> 5;

    STAGE(0, 0);                        // prologue: tile 0 -> buf 0 (async)

    for (int kk = 0; kk < nk; kk++) {
        const int cur = kk & 1;
        __syncthreads();               // vmcnt+lgkm drain: tile kk resident in buf cur
        if (kk + 1 < nk)
            STAGE(cur ^ 1, (long)(kk + 1) << 5);   // in flight across this compute phase

        const _Float16* cA = &sA[cur][0];
        const _Float16* cB = &sB[cur][0];
        half8 af[4], bf[4];
#pragma unroll
        for (int t = 0; t < 4; t++)
            af[t] = *(const half8*)&cA[(wr * 64 + t * 16 + l16) * 32 + aoff];
#pragma unroll
        for (int t = 0; t < 4; t++)
            bf[t] = *(const half8*)&cB[(wc * 64 + t * 16 + l16) * 32 + aoff];
#pragma unroll
        for (int tm = 0; tm < 4; tm++)
#pragma unroll
            for (int tn = 0; tn < 4; tn++)
                acc[tm][tn] = __builtin_amdgcn_mfma_f32_16x16x32_f16(af[tm], bf[tn], acc[tm][tn], 0, 0, 0);
    }
#undef STAGE

    // epilogue: C/D layout col=lane&15, row=quad*4+reg (verified m89/m91)
#pragma unroll
    for (int tm = 0; tm < 4; tm++) {
        long row = m0 + wr * 64 + tm * 16 + quad * 4;
#pragma unroll
        for (int tn = 0; tn < 4; tn++) {
            long col = n0 + wc * 64 + tn * 16 + l16;
            if (Cf) {
                float bv = bias ? bias[col] : 0.f;
#pragma unroll
                for (int r = 0; r < 4; r++)
                    Cf[(row + r) * (long)Nn + col] = acc[tm][tn][r] + bv;
            } else if (col >= split) {
                // transposed V write: Vt[(b*16+h)*64+d][n], n = 4 consecutive rows
                long cv = col - split;
                long vrow = ((row >> 10) * 16 + (cv >> 6)) * 64 + (cv & 63);
                long nn = row & 1023;
                half4v pv = {(_Float16)acc[tm][tn][0], (_Float16)acc[tm][tn][1],
                             (_Float16)acc[tm][tn][2], (_Float16)acc[tm][tn][3]};
                *(half4v*)&Vt[vrow * 1024 + nn] = pv;
            } else {
#pragma unroll
                for (int r = 0; r < 4; r++)
                    Ch[(row + r) * (long)ldc + col] = (_Float16)acc[tm][tn][r];
            }
        }
    }
}

// ---------------- flash attention (S^T orientation) ----------------
#define CSC 0.125f
__global__ __launch_bounds__(256, 4) void flash_attn(const _Float16* __restrict__ qk,
                                                     const _Float16* __restrict__ vt,
                                                     _Float16* __restrict__ out)
{
    const int bh = blockIdx.x, b = bh >> 4, h = bh & 15;
    const int n0 = blockIdx.y * 128;
    const int tid = threadIdx.x, lane = tid & 63, wave = tid >> 6;
    const int quad = lane >> 4, l16 = lane & 15;

    __shared__ _Float16 sK[64 * 72];        // [kr][d] pad 72
    __shared__ _Float16 sVT[64 * 72];       // [d][kr] pad 72
    __shared__ _Float16 sPT[4][32 * 72];    // per-wave P^T round-trip [q][kr], reused as sOut

    half8 qf[2][2];
    const _Float16* qbase = qk + (long)(b * 1024 + n0 + wave * 32) * 2048 + h * 64;
#pragma unroll
    for (int t = 0; t < 2; t++)
#pragma unroll
        for (int s = 0; s < 2; s++)
            qf[t][s] = *(const half8*)(qbase + (long)(t * 16 + l16) * 2048 + s * 32 + quad * 8);

    const int srow = tid >> 3, scol8 = (tid & 7) * 8;
    const _Float16* kgb = qk + 1024 + h * 64 + scol8 + (long)(b * 1024 + srow) * 2048;
    const _Float16* vgb = vt + (long)(bh * 64 + srow) * 1024 + scol8;

    float m_[2] = {-1e30f, -1e30f}, l_[2] = {0.f, 0.f};
    floatx4 o[2][4] = {};

    for (int kt = 0; kt < 16; kt++) {
        const int kr0 = kt * 64;
        __syncthreads();
#pragma unroll
        for (int i = 0; i < 2; i++) {
            int r = srow + i * 32;
            *(half8*)&sK[r * 72 + scol8]  = *(const half8*)(kgb + (long)(kr0 + i * 32) * 2048);
            *(half8*)&sVT[r * 72 + scol8] = *(const half8*)(vgb + (long)(i * 32) * 1024 + kr0);
        }
        __syncthreads();

        // S^T = K Q^T: A=K (m=kr), B=Q (n=q). C-layout: kr=c*16+quad*4+r, q=t*16+l16
        floatx4 sacc[2][4] = {};
#pragma unroll
        for (int c = 0; c < 4; c++)
#pragma unroll
            for (int s = 0; s < 2; s++) {
                half8 kf = *(const half8*)&sK[(c * 16 + l16) * 72 + s * 32 + quad * 8];
                sacc[0][c] = __builtin_amdgcn_mfma_f32_16x16x32_f16(kf, qf[0][s], sacc[0][c], 0, 0, 0);
                sacc[1][c] = __builtin_amdgcn_mfma_f32_16x16x32_f16(kf, qf[1][s], sacc[1][c], 0, 0, 0);
            }

        // online softmax over kr: in-lane reduce + 2 shuffles (xor16, xor32)
#pragma unroll
        for (int t = 0; t < 2; t++) {
            float mx = -1e30f;
#pragma unroll
            for (int c = 0; c < 4; c++)
#pragma unroll
                for (int r = 0; r < 4; r++) {
                    float v = sacc[t][c][r] * CSC;
                    sacc[t][c][r] = v;
                    mx = fmaxf(mx, v);
                }
            mx = fmaxf(mx, __shfl_xor(mx, 16));
            mx = fmaxf(mx, __shfl_xor(mx, 32));
            float mn = fmaxf(m_[t], mx);
            float al = __expf(m_[t] - mn);
            m_[t] = mn;
            float rs = 0.f;
#pragma unroll
            for (int c = 0; c < 4; c++)
#pragma unroll
                for (int r = 0; r < 4; r++) {
                    float p = __expf(sacc[t][c][r] - mn);
                    sacc[t][c][r] = p;
                    rs += p;
                }
            rs += __shfl_xor(rs, 16);
            rs += __shfl_xor(rs, 32);
            l_[t] = l_[t] * al + rs;
#pragma unroll
            for (int dt = 0; dt < 4; dt++) o[t][dt] *= al;
            // pack P^T -> sPT[q][kr], one 8B half4 write per c-tile
#pragma unroll
            for (int c = 0; c < 4; c++) {
                half4v p = {(_Float16)sacc[t][c][0], (_Float16)sacc[t][c][1],
                            (_Float16)sacc[t][c][2], (_Float16)sacc[t][c][3]};
                *(half4v*)&sPT[wave][(t * 16 + l16) * 72 + c * 16 + quad * 4] = p;
            }
        }

        // PV: O^T += V^T P^T. A = V^T (m=d), B = P (n=q) from sPT.
#pragma unroll
        for (int kk = 0; kk < 2; kk++) {
            half8 pf0 = *(const half8*)&sPT[wave][(l16) * 72 + kk * 32 + quad * 8];
            half8 pf1 = *(const half8*)&sPT[wave][(16 + l16) * 72 + kk * 32 + quad * 8];
#pragma unroll
            for (int dt = 0; dt < 4; dt++) {
                half8 vf = *(const half8*)&sVT[(dt * 16 + l16) * 72 + kk * 32 + quad * 8];
                o[0][dt] = __builtin_amdgcn_mfma_f32_16x16x32_f16(vf, pf0, o[0][dt], 0, 0, 0);
                o[1][dt] = __builtin_amdgcn_mfma_f32_16x16x32_f16(vf, pf1, o[1][dt], 0, 0, 0);
            }
        }
    }

    // epilogue: normalize, per-wave LDS transpose (O^T -> O), coalesced 16B stores
#pragma unroll
    for (int t = 0; t < 2; t++) {
        float inv = 1.f / l_[t];
#pragma unroll
        for (int dt = 0; dt < 4; dt++) {
            floatx4 v = o[t][dt];
            half4v a = {(_Float16)(v[0] * inv), (_Float16)(v[1] * inv),
                        (_Float16)(v[2] * inv), (_Float16)(v[3] * inv)};
            *(half4v*)&sPT[wave][(t * 16 + l16) * 72 + dt * 16 + quad * 4] = a;
        }
    }
    __syncthreads();
#pragma unroll
    for (int i = 0; i < 4; i++) {
        int ql = i * 8 + (lane >> 3);
        int c8 = (lane & 7) * 8;
        half8 vv = *(const half8*)&sPT[wave][ql * 72 + c8];
        *(half8*)(out + (long)(b * 1024 + n0 + wave * 32 + ql) * 1024 + h * 64 + c8) = vv;
    }
}

// ---------------- launch ----------------
extern "C" void kernel_launch(void* const* d_in, const int* in_sizes, int n_in,
                              void* d_out, int out_size, void* d_ws, size_t ws_size,
                              hipStream_t stream) {
    const float* x      = (const float*)d_in[0];
    const float* w_qkv  = (const float*)d_in[1];
    const float* w_proj = (const float*)d_in[2];
    const float* b_proj = (const float*)d_in[3];

    char* ws = (char*)d_ws;
    _Float16* qkh    = (_Float16*)ws;                      // 32MB [8192][2048] (Q|K)
    _Float16* vT     = (_Float16*)(ws + 33554432);         // 16MB [128*64][1024] (V^T), by GEMM1
    _Float16* xh     = (_Float16*)(ws + 50331648);         // 16MB [8192][1024]; attnh alias
    _Float16* wqkvh  = (_Float16*)(ws + 67108864);         // 6MB [3072][1024]
    _Float16* wprojh = (_Float16*)(ws + 73400320);         // 2MB [1024][1024]
    _Float16* attnh  = xh;                                 // flash out (xh dead after GEMM1)

    cvt_all<<<12288, 256, 0, stream>>>(x, w_qkv, w_proj, xh, wqkvh, wprojh);

    // QKV GEMM: cols 0..2047 -> qkh row-major, cols 2048..3071 -> vT transposed
    gemm_tn<<<dim3(64, 24), 256, 0, stream>>>(xh, wqkvh, qkh, 2048, vT, 2048,
                                              nullptr, nullptr, 8192, 3072, 1024);
    flash_attn<<<dim3(128, 8), 256, 0, stream>>>(qkh, vT, attnh);
    gemm_tn<<<dim3(64, 8), 256, 0, stream>>>(attnh, wprojh, nullptr, 0, nullptr, 1 << 30,
                                             (float*)d_out, b_proj, 8192, 1024, 1024);
}